// Round 2
// baseline (476.303 us; speedup 1.0000x reference)
//
#include <hip/hip_runtime.h>

#define LL 256   // sequence length
#define EE 64    // embed dim
#define HH 64    // hidden dim
#define GG 256   // 4*H gates
#define NSEQ 8   // valid sequences per block (rows 8-15 of MFMA tile are waste)
#define MROW 16  // MFMA M rows (fixed by the 16x16x32 shape)
#define ROWP 72  // padded LDS row stride in bf16 elems (144 B, 16B-aligned)

typedef __bf16 bf16_t;
typedef bf16_t bf16x8 __attribute__((ext_vector_type(8)));
typedef float  f32x4  __attribute__((ext_vector_type(4)));

union BfPack {
    unsigned short u[8];
    bf16x8 v;
};

// compiler cast -> v_cvt(_pk)_bf16_f32 (RNE), ~1 op vs 4-op manual round
__device__ __forceinline__ unsigned short f2bf(float f) {
    return __builtin_bit_cast(unsigned short, (__bf16)f);
}

#define LOG2E 1.44269504088896340736f

// exp2+rcp activations, no IEEE divide sequences. Both forms are Inf-safe:
// x->+inf: exp2->inf, rcp(inf)=0 -> correct saturation; no clamps needed.
__device__ __forceinline__ float sigm(float x) {
    float e = __builtin_amdgcn_exp2f(-LOG2E * x);          // e^{-x}
    return __builtin_amdgcn_rcpf(1.0f + e);
}
__device__ __forceinline__ float tanh_fast(float x) {
    float e = __builtin_amdgcn_exp2f((2.0f * LOG2E) * x);  // e^{2x}
    return 1.0f - 2.0f * __builtin_amdgcn_rcpf(e + 1.0f);
}

// lgkm-only barrier: cross-wave deps each timestep are LDS-only. Keeping
// vmcnt out of the barrier lets the 4 scattered HBM out-stores retire
// asynchronously across the next timestep (R0->R1: 567 -> 415 us).
#define LGKM_BARRIER() asm volatile("s_waitcnt lgkmcnt(0)\n\ts_barrier" ::: "memory")

// One block = 8 sequences, one direction, 4 waves. NSEQ=8 (not 16) so TWO
// blocks co-reside per CU -> 2 waves/SIMD: independent recurrences interleave
// and fill each other's dependency stalls (R1 counters: 1 wave/SIMD, VALUBusy
// 53% -> 47% idle with nothing to hide it). Rows 8-15 of each MFMA tile are
// dead weight (MfmaUtil was 13.5%, can afford 2x).
__global__ __launch_bounds__(256, 2)
void bilstm_mfma(const int* __restrict__ ids,
                 const float* __restrict__ embed,
                 const float* __restrict__ Wk_f, const float* __restrict__ Wr_f,
                 const float* __restrict__ b_f,
                 const float* __restrict__ Wk_b, const float* __restrict__ Wr_b,
                 const float* __restrict__ b_b,
                 float* __restrict__ out)
{
    const int dir = blockIdx.x >> 8;    // 0 fwd (blocks 0-255), 1 bwd
    const int grp = blockIdx.x & 255;
    const int n0  = grp * NSEQ;
    const int tid  = threadIdx.x;
    const int w    = tid >> 6;
    const int lane = tid & 63;
    const int l15  = lane & 15;
    const int quad = lane >> 4;
    const int j    = w * 16 + l15;      // gate sub-index in [0,64)

    const float* Wk = dir ? Wk_b : Wk_f;
    const float* Wr = dir ? Wr_b : Wr_f;
    const float* bv = dir ? b_b  : b_f;

    __shared__ __align__(16) short s_x[2][MROW][ROWP];  // 4.5 KB
    __shared__ __align__(16) short s_h[2][MROW][ROWP];  // 4.5 KB
    __shared__ int s_ids[NSEQ][LL];                     // 8 KB

    // stage ids (coalesced)
    for (int p = tid; p < NSEQ * LL; p += 256) {
        int m = p >> 8, t = p & 255;
        s_ids[m][t] = ids[(size_t)(n0 + m) * LL + t];
    }
    // zero both h buffers AND both x buffers: rows 8-15 are never written
    // again, so MFMA D-rows 8-15 stay clean (= bias), no garbage in trans ops.
    for (int p = tid; p < 2 * MROW * ROWP; p += 256) {
        (&s_h[0][0][0])[p] = 0;
        (&s_x[0][0][0])[p] = 0;
    }

    __syncthreads();   // s_ids/s_h/s_x visible to all waves

    // B fragments (bf16) + bias C-fragments, register-resident all kernel.
    // B-frag layout: lane holds B[k = kc*32 + quad*8 + e][n = l15], e=0..7.
    bf16x8 bfrag[4][4];   // [gate tt][k-chunk]
    f32x4  biasC[4];
    #pragma unroll
    for (int tt = 0; tt < 4; ++tt) {
        int g = tt * 64 + j;            // global gate column
        float bb = bv[g];
        biasC[tt] = (f32x4){bb, bb, bb, bb};
        #pragma unroll
        for (int kc = 0; kc < 4; ++kc) {
            BfPack pk;
            #pragma unroll
            for (int e = 0; e < 8; ++e) {
                int kg = kc * 32 + quad * 8 + e;
                float v = (kg < 64) ? Wk[(size_t)kg * GG + g]
                                    : Wr[(size_t)(kg - 64) * GG + g];
                pk.u[e] = f2bf(v);
            }
            bfrag[tt][kc] = pk.v;
        }
    }

    // gather x for the first step into buffer 0 (rows 0..7, one float2/thread)
    {
        int t0 = dir ? (LL - 1) : 0;
        int m = tid >> 5, ep = tid & 31;
        int id = s_ids[m][t0];
        float2 xv = *(const float2*)&embed[(size_t)id * EE + 2 * ep];
        unsigned pk = (unsigned)f2bf(xv.x) | ((unsigned)f2bf(xv.y) << 16);
        *(unsigned*)&s_x[0][m][2 * ep] = pk;
    }
    __syncthreads();

    float c[4] = {0.f, 0.f, 0.f, 0.f};   // cell state for rows m = quad*4+r
    const f32x4 zero4 = (f32x4){0.f, 0.f, 0.f, 0.f};

    // strength-reduced out pointers: advance by +-256 floats per timestep
    // instead of re-deriving the 64-bit address each step
    const int tstep = dir ? -(2 * HH) : (2 * HH);
    float* optr[4];
    {
        const int t0 = dir ? (LL - 1) : 0;
        #pragma unroll
        for (int r = 0; r < 4; ++r) {
            int m = quad * 4 + r;
            int mm = (m < NSEQ) ? m : 0;    // invalid lanes: valid dummy ptr, never stored
            optr[r] = out + ((size_t)(n0 + mm) * LL + t0) * (2 * HH) + dir * HH + j;
        }
    }

    for (int ts = 0; ts < LL; ++ts) {
        const int rb = ts & 1, wb = (ts + 1) & 1;

        // issue prefetch of x_{ts+1} early (embed table is L2/L3-resident)
        float2 px0;
        const int pm0 = tid >> 5, pe = tid & 31;
        const bool pf = (ts + 1 < LL);
        if (pf) {
            int tn = dir ? (LL - 2 - ts) : (ts + 1);
            px0 = *(const float2*)&embed[(size_t)s_ids[pm0][tn] * EE + 2 * pe];
        }

        // A fragments: lane reads A[m = l15][k = quad*8 .. +7] (ds_read_b128)
        bf16x8 ax0 = *(const bf16x8*)&s_x[rb][l15][quad * 8];
        bf16x8 ax1 = *(const bf16x8*)&s_x[rb][l15][32 + quad * 8];
        bf16x8 ah0 = *(const bf16x8*)&s_h[rb][l15][quad * 8];
        bf16x8 ah1 = *(const bf16x8*)&s_h[rb][l15][32 + quad * 8];

        // z = (bias + x@Wk) + (h@Wr): two independent 2-deep MFMA chains per
        // gate; critical path is 2 MFMA latencies, not 4.
        f32x4 acc[4];
        #pragma unroll
        for (int tt = 0; tt < 4; ++tt) {
            f32x4 axc = __builtin_amdgcn_mfma_f32_16x16x32_bf16(ax0, bfrag[tt][0], biasC[tt], 0, 0, 0);
            axc = __builtin_amdgcn_mfma_f32_16x16x32_bf16(ax1, bfrag[tt][1], axc, 0, 0, 0);
            f32x4 ahc = __builtin_amdgcn_mfma_f32_16x16x32_bf16(ah0, bfrag[tt][2], zero4, 0, 0, 0);
            ahc = __builtin_amdgcn_mfma_f32_16x16x32_bf16(ah1, bfrag[tt][3], ahc, 0, 0, 0);
            acc[tt] = axc + ahc;
        }

        // gate math in-register; C/D layout: row m = quad*4 + r, col = l15.
        // Rows >= NSEQ (quads 2,3) compute on clean bias values, stores masked.
        #pragma unroll
        for (int r = 0; r < 4; ++r) {
            float ig = sigm(acc[0][r]);
            float fg = sigm(acc[1][r]);
            float gg = tanh_fast(acc[2][r]);
            float og = sigm(acc[3][r]);
            c[r] = fg * c[r] + ig * gg;
            float hh = og * tanh_fast(c[r]);
            if (quad < 2) {
                *optr[r] = hh;
                s_h[wb][quad * 4 + r][j] = (short)f2bf(hh);
            }
            optr[r] += tstep;
        }

        // commit prefetched x into the write buffer (rows 0..7)
        if (pf) {
            unsigned pk0 = (unsigned)f2bf(px0.x) | ((unsigned)f2bf(px0.y) << 16);
            *(unsigned*)&s_x[wb][pm0][2 * pe] = pk0;
        }
        // orders LDS wb-buffer writes before next step's reads; does NOT
        // drain the global out-store queue (no reader -> async retire)
        LGKM_BARRIER();
    }
}

extern "C" void kernel_launch(void* const* d_in, const int* in_sizes, int n_in,
                              void* d_out, int out_size, void* d_ws, size_t ws_size,
                              hipStream_t stream) {
    const int*   ids   = (const int*)d_in[0];
    const float* embed = (const float*)d_in[1];
    const float* Wk_f  = (const float*)d_in[2];
    const float* Wr_f  = (const float*)d_in[3];
    const float* b_f   = (const float*)d_in[4];
    const float* Wk_b  = (const float*)d_in[5];
    const float* Wr_b  = (const float*)d_in[6];
    const float* b_b   = (const float*)d_in[7];
    float* out = (float*)d_out;

    dim3 grid(512);   // 256 seq-groups x 2 directions, 8 seqs each -> 2 blocks/CU
    dim3 block(256);
    bilstm_mfma<<<grid, block, 0, stream>>>(ids, embed,
                                            Wk_f, Wr_f, b_f,
                                            Wk_b, Wr_b, b_b,
                                            out);
}

// Round 3
// 430.912 us; speedup vs baseline: 1.1053x; 1.1053x over previous
//
#include <hip/hip_runtime.h>

#define LL 256   // sequence length
#define EE 64    // embed dim
#define HH 64    // hidden dim
#define GG 256   // 4*H gates
#define VV 6000  // vocab
#define NSEQ 16  // sequences per block (full MFMA tile, no waste)
#define ROWP 72  // padded LDS row stride in bf16 elems (144 B, 16B-aligned)
#define VBLK 375 // phase-1 blocks per direction (6000/16)

typedef __bf16 bf16_t;
typedef bf16_t bf16x8 __attribute__((ext_vector_type(8)));
typedef float  f32x4  __attribute__((ext_vector_type(4)));

union BfPack {
    unsigned short u[8];
    bf16x8 v;
};

__device__ __forceinline__ unsigned short f2bf(float f) {
    return __builtin_bit_cast(unsigned short, (__bf16)f);
}

#define LOG2E 1.44269504088896340736f

// exp2+rcp activations (R1: removed IEEE div sequences). Inf-safe both ends.
__device__ __forceinline__ float sigm(float x) {
    float e = __builtin_amdgcn_exp2f(-LOG2E * x);          // e^{-x}
    return __builtin_amdgcn_rcpf(1.0f + e);
}
__device__ __forceinline__ float tanh_fast(float x) {
    float e = __builtin_amdgcn_exp2f((2.0f * LOG2E) * x);  // e^{2x}
    return 1.0f - 2.0f * __builtin_amdgcn_rcpf(e + 1.0f);
}

// lgkm-only barrier (R0->R1: 567->415 us): cross-wave deps are LDS-only;
// out-stores retire asynchronously across the next timestep.
#define LGKM_BARRIER() asm volatile("s_waitcnt lgkmcnt(0)\n\ts_barrier" ::: "memory")

// ---------------- phase 1: embedPre[dir][v][swz(g)] = embed@Wk + b ----------
// x_t @ Wk == (embed @ Wk)[id] : the whole input projection is a table.
// Swizzled layout: pos = ((g>>4)&3)*64 + (g&15)*4 + (g>>6), so that phase-2
// lane (w,quad,l15) reads its 4 gate values for one seq-row as ONE dwordx4 at
// [id*256 + w*64 + l15*4], 16 lanes = 256 B contiguous per quad-group.
__global__ __launch_bounds__(256)
void embed_pre_kernel(const float* __restrict__ embed,
                      const float* __restrict__ Wk_f, const float* __restrict__ b_f,
                      const float* __restrict__ Wk_b, const float* __restrict__ b_b,
                      float* __restrict__ pre)
{
    const int bid = blockIdx.x;
    const int dir = bid / VBLK;
    const int v0  = (bid % VBLK) * 16;
    const float* Wk = dir ? Wk_b : Wk_f;
    const float* bv = dir ? b_b  : b_f;
    float* dst = pre + (size_t)dir * VV * GG;

    const int tid = threadIdx.x;
    const int r   = tid >> 4;    // v-row 0..15
    const int cg  = tid & 15;    // col residue; thread owns g = k*16+cg

    __shared__ float sW[16][GG];   // 16 KB per E-chunk
    __shared__ float sE[16][17];   // 16 rows x 16 e, padded

    float acc[16];
    #pragma unroll
    for (int k = 0; k < 16; ++k) acc[k] = 0.f;

    for (int ec = 0; ec < 4; ++ec) {
        {   // stage Wk rows ec*16..+15 (coalesced float4) + embed chunk
            int er = tid >> 4;
            int c0 = (tid & 15) * 16;
            const float* src = &Wk[(size_t)(ec * 16 + er) * GG + c0];
            *(float4*)&sW[er][c0 + 0]  = *(const float4*)(src + 0);
            *(float4*)&sW[er][c0 + 4]  = *(const float4*)(src + 4);
            *(float4*)&sW[er][c0 + 8]  = *(const float4*)(src + 8);
            *(float4*)&sW[er][c0 + 12] = *(const float4*)(src + 12);
            sE[er][tid & 15] = embed[(size_t)(v0 + er) * EE + ec * 16 + (tid & 15)];
        }
        __syncthreads();
        #pragma unroll
        for (int e = 0; e < 16; ++e) {
            float xe = sE[r][e];
            #pragma unroll
            for (int k = 0; k < 16; ++k)
                acc[k] += xe * sW[e][k * 16 + cg];   // 16 consecutive banks, CF
        }
        __syncthreads();
    }
    #pragma unroll
    for (int k = 0; k < 16; ++k) {
        int g = k * 16 + cg;
        int pos = ((g >> 4) & 3) * 64 + (g & 15) * 4 + (g >> 6);
        dst[(size_t)(v0 + r) * GG + pos] = acc[k] + bv[g];
    }
}

// ---------------- phase 2: recurrence only (h@Wr per step) ------------------
// One block = 16 seqs, one direction, 4 waves. Per wave per step: 4 dwordx4
// pre-gathers (prefetched 1 step ahead, seed the MFMA C operand), 2
// ds_read_b128 (h fragments), 8 MFMAs (4 gates x 2-deep K=64 chain), gate
// math, 4 out stores, 4 ds_write_b16 (h), one lgkm-only barrier.
__global__ __launch_bounds__(256, 1)
void bilstm_mfma(const int* __restrict__ ids,
                 const float* __restrict__ Wr_f, const float* __restrict__ Wr_b,
                 const float* __restrict__ pre,
                 float* __restrict__ out)
{
    const int dir = blockIdx.x >> 7;    // 0 fwd, 1 bwd
    const int grp = blockIdx.x & 127;
    const int n0  = grp * NSEQ;
    const int tid  = threadIdx.x;
    const int w    = tid >> 6;
    const int lane = tid & 63;
    const int l15  = lane & 15;
    const int quad = lane >> 4;
    const int j    = w * 16 + l15;      // gate sub-index in [0,64)

    const float* Wr = dir ? Wr_b : Wr_f;
    const float* preT = pre + (size_t)dir * VV * GG;
    const int coff = w * 64 + l15 * 4;  // lane's fixed swizzled col offset

    __shared__ __align__(16) short s_h[2][NSEQ][ROWP];  // 4.5 KB
    __shared__ int s_ids[NSEQ][LL + 1];                 // padded: row stride 257

    // stage ids (coalesced)
    for (int p = tid; p < NSEQ * LL; p += 256) {
        int m = p >> 8, t = p & 255;
        s_ids[m][t] = ids[(size_t)(n0 + m) * LL + t];
    }
    // zero both h buffers (h0 = 0)
    for (int p = tid; p < 2 * NSEQ * ROWP; p += 256)
        (&s_h[0][0][0])[p] = 0;

    __syncthreads();

    // Wr B-fragments only (K=64): lane holds B[k = kc*32 + quad*8 + e][l15]
    bf16x8 bfrag[4][2];
    #pragma unroll
    for (int tt = 0; tt < 4; ++tt) {
        int g = tt * 64 + j;
        #pragma unroll
        for (int kc = 0; kc < 2; ++kc) {
            BfPack pk;
            #pragma unroll
            for (int e = 0; e < 8; ++e) {
                int kg = kc * 32 + quad * 8 + e;
                pk.u[e] = f2bf(Wr[(size_t)kg * GG + g]);
            }
            bfrag[tt][kc] = pk.v;
        }
    }

    // gather pre for the first step into registers
    f32x4 curP[4];
    {
        int t0 = dir ? (LL - 1) : 0;
        #pragma unroll
        for (int r = 0; r < 4; ++r) {
            int id = s_ids[quad * 4 + r][t0];
            curP[r] = *(const f32x4*)&preT[(size_t)id * GG + coff];
        }
    }

    float c[4] = {0.f, 0.f, 0.f, 0.f};

    // strength-reduced out pointers: advance +-256 floats per timestep
    const int tstep = dir ? -(2 * HH) : (2 * HH);
    float* optr[4];
    {
        const int t0 = dir ? (LL - 1) : 0;
        #pragma unroll
        for (int r = 0; r < 4; ++r)
            optr[r] = out + ((size_t)(n0 + quad * 4 + r) * LL + t0) * (2 * HH) + dir * HH + j;
    }

    for (int ts = 0; ts < LL; ++ts) {
        const int rb = ts & 1, wb = (ts + 1) & 1;

        // prefetch pre rows for t+1 (L2/L3-resident table, hidden under step)
        f32x4 nxtP[4];
        const bool pf = (ts + 1 < LL);
        if (pf) {
            int tn = dir ? (LL - 2 - ts) : (ts + 1);
            #pragma unroll
            for (int r = 0; r < 4; ++r) {
                int id = s_ids[quad * 4 + r][tn];
                nxtP[r] = *(const f32x4*)&preT[(size_t)id * GG + coff];
            }
        }

        // h A-fragments: lane reads A[m=l15][k=quad*8..+7] (ds_read_b128)
        bf16x8 ah0 = *(const bf16x8*)&s_h[rb][l15][quad * 8];
        bf16x8 ah1 = *(const bf16x8*)&s_h[rb][l15][32 + quad * 8];

        // z = pre (C-seed, bias+x@Wk folded) + h@Wr : 4 independent 2-deep chains
        f32x4 acc[4];
        #pragma unroll
        for (int tt = 0; tt < 4; ++tt) {
            f32x4 cIn = (f32x4){curP[0][tt], curP[1][tt], curP[2][tt], curP[3][tt]};
            f32x4 a = __builtin_amdgcn_mfma_f32_16x16x32_bf16(ah0, bfrag[tt][0], cIn, 0, 0, 0);
            acc[tt]  = __builtin_amdgcn_mfma_f32_16x16x32_bf16(ah1, bfrag[tt][1], a, 0, 0, 0);
        }

        // gate math; C/D layout: row m = quad*4 + r, col = l15
        #pragma unroll
        for (int r = 0; r < 4; ++r) {
            float ig = sigm(acc[0][r]);
            float fg = sigm(acc[1][r]);
            float gg = tanh_fast(acc[2][r]);
            float og = sigm(acc[3][r]);
            c[r] = fg * c[r] + ig * gg;
            float hh = og * tanh_fast(c[r]);
            *optr[r] = hh;
            optr[r] += tstep;
            s_h[wb][quad * 4 + r][j] = (short)f2bf(hh);
        }

        #pragma unroll
        for (int r = 0; r < 4; ++r) curP[r] = nxtP[r];

        // orders LDS h-writes before next step's reads; no vmcnt drain
        LGKM_BARRIER();
    }
}

extern "C" void kernel_launch(void* const* d_in, const int* in_sizes, int n_in,
                              void* d_out, int out_size, void* d_ws, size_t ws_size,
                              hipStream_t stream) {
    const int*   ids   = (const int*)d_in[0];
    const float* embed = (const float*)d_in[1];
    const float* Wk_f  = (const float*)d_in[2];
    const float* Wr_f  = (const float*)d_in[3];
    const float* b_f   = (const float*)d_in[4];
    const float* Wk_b  = (const float*)d_in[5];
    const float* Wr_b  = (const float*)d_in[6];
    const float* b_b   = (const float*)d_in[7];
    float* out = (float*)d_out;
    float* pre = (float*)d_ws;   // 2 * 6000 * 256 * 4 B = 12.3 MB

    embed_pre_kernel<<<dim3(2 * VBLK), dim3(256), 0, stream>>>(
        embed, Wk_f, b_f, Wk_b, b_b, pre);

    bilstm_mfma<<<dim3(256), dim3(256), 0, stream>>>(ids, Wr_f, Wr_b, pre, out);
}